// Round 5
// baseline (239.104 us; speedup 1.0000x reference)
//
#include <hip/hip_runtime.h>
#include <hip/hip_bf16.h>
#include <hip/hip_fp16.h>

// Problem: pooled = tanh(hs @ W^T + b); out0 = pooled[:,0]; out1 = span-means;
// out2 = zeros(N,S).  N=64, L=512, H=768, S=16. Inputs fp32, d_out fp32.
//
// R10: R9 K-loop untouched; epilogue rebuilt ATOMIC-FREE.
// Theory: every prior version (118-160 us) carried ~15k serialized atomic
// RMWs per block (global in R5-R7, LDS in R8-R9) contending on 16x96 hot
// addresses -- ~120-240k cyc/CU, the same magnitude as the whole kernel wall,
// invisible to MfmaUtil/VALUBusy/HBM counters. This round: after the K-loop
// Wl is dead; alias it as fp16 pooled[96][516] (tanh in (-1,1): fp16 err
// <=5e-4, far under the 5.9e-3 bf16-input noise). Each thread writes its 48
// tanh values as 12 x ds_write_b64, barrier, then threads own (span,col)
// pairs and serially sum rows -- zero atomics anywhere.
#define NPASS 64
#define LSEQ  512
#define HDIM  768
#define NSPAN 16
#define OFF_SENT (NPASS*HDIM)                     // 49152
#define OFF_MASK (OFF_SENT + NPASS*NSPAN*HDIM)    // 835584

#define BN   96
#define NTN  6                     // BN/16 fragments per wave
#define BK   32
#define NK   (HDIM/BK)             // 24
#define NTILES (HDIM/BN)           // 8
#define NBLK (NPASS*NTILES)        // 512  (2 rounds on 256 CUs)
#define THREADS 1024
#define NMT  2                     // row-fragments per wave (32 rows/wave)
#define PSTR 516                   // pooled LDS stride (halfs); 516*2B, bank-spread

typedef __bf16 bf16x8 __attribute__((ext_vector_type(8)));
typedef __bf16 bf16x4 __attribute__((ext_vector_type(4)));
typedef float  f32x4  __attribute__((ext_vector_type(4)));

// tanh via v_exp_f32: ~7 VALU ops vs ~25 for libm tanhf. |err| < 1e-6 rel.
__device__ inline float fast_tanh(float x) {
  const float ax = fabsf(x);
  const float t  = __expf(-2.0f * ax);
  const float r  = (1.0f - t) * __builtin_amdgcn_rcpf(1.0f + t);
  return copysignf(r, x);
}

// 8x fp32 -> bf16x8 (RNE via fptrunc; compiler emits v_cvt_pk_bf16_f32 pairs).
__device__ inline bf16x8 cvt8(f32x4 lo, f32x4 hi) {
  union { bf16x4 h[2]; bf16x8 v; } u;
  u.h[0] = __builtin_convertvector(lo, bf16x4);
  u.h[1] = __builtin_convertvector(hi, bf16x4);
  return u.v;
}

__global__ __launch_bounds__(THREADS, 4) void fused_kernel(
    const float* __restrict__ A,        // (32768, 768) fp32
    const float* __restrict__ W,        // (768, 768) fp32, row o contiguous in h
    const float* __restrict__ bias,     // (768,)
    const int*   __restrict__ spans,    // (64,16,2)
    float* __restrict__ out)
{
  __shared__ __align__(16) unsigned short Wl[BN * HDIM];   // 147456 B bf16
  // After the K-loop Wl is dead; aliased as __half P[BN][PSTR] = 99 KB.
  __shared__ int   sp_st[NSPAN], sp_en[NSPAN];
  __shared__ float inv_s[NSPAN];
  __shared__ float bias_s[BN];
  // total ~148 KB -> 1 block/CU, 16 waves (4/SIMD)

  const int tid = threadIdx.x;
  const int b   = blockIdx.x;
  // XCD swizzle (bijective, 512 = 64*8): 8 sibling N-tiles of a passage land
  // consecutive on one XCD -> passage's 1.5 MB A-slice L2-shared.
  const int xcd = b & 7;
  const int t   = b >> 3;                 // 0..63 per XCD
  const int p   = ((t >> 3) << 3) | xcd;  // passage 0..63
  const int ntb = t & 7;                  // N-tile 0..7
  const int tile_n = ntb * BN;

  // ---- Prologue ----

  // 1) Stage W slice: fp32 global -> cvt -> bf16 LDS, XOR-swizzled.
  //    Layout: Wl[wr][kg'] with kg' = kg ^ (wr&7) over 16B granules (8 bf16).
  {
    const float* Wp = W + (size_t)tile_n * HDIM;
    #pragma unroll
    for (int j = 0; j < (BN * (HDIM / 8)) / THREADS; ++j) {
      const int g  = j * THREADS + tid;
      const int wr = g / (HDIM / 8);        // 0..95  (W row = output col)
      const int kg = g % (HDIM / 8);        // 0..95  (16B granule in K)
      const float* src = Wp + (size_t)wr * HDIM + kg * 8;
      const f32x4 lo = *(const f32x4*)src;
      const f32x4 hi = *(const f32x4*)(src + 4);
      const int kgs = kg ^ (wr & 7);
      *(bf16x8*)(Wl + (size_t)wr * HDIM + kgs * 8) = cvt8(lo, hi);
    }
  }

  // 2) Span tables (no per-row sid needed anymore).
  if (tid < NSPAN) {
    const int st = spans[(p * NSPAN + tid) * 2 + 0];
    const int en = spans[(p * NSPAN + tid) * 2 + 1];
    sp_st[tid] = st; sp_en[tid] = en;
    inv_s[tid] = 1.0f / (float)(en - st);
  }
  if (tid >= 512 && tid < 512 + BN) bias_s[tid - 512] = bias[tile_n + tid - 512];

  __syncthreads();

  // ---- Zero-barrier K-loop (identical to R9) ----
  const int wave = tid >> 6;            // 0..15 -> rows [wave*32, wave*32+32)
  const int lane = tid & 63;
  const int quad = lane >> 4;
  const int lr   = lane & 15;

  const float* Ab = A + ((size_t)p * LSEQ + wave * 32 + lr) * HDIM + quad * 8;

  f32x4 acc[NMT][NTN];
  #pragma unroll
  for (int mt = 0; mt < NMT; ++mt)
    #pragma unroll
    for (int nt = 0; nt < NTN; ++nt)
      acc[mt][nt] = (f32x4){0.f, 0.f, 0.f, 0.f};

  f32x4 alo[NMT], ahi[NMT];
  #pragma unroll
  for (int mt = 0; mt < NMT; ++mt) {
    const float* s0 = Ab + (size_t)mt * 16 * HDIM;
    alo[mt] = *(const f32x4*)s0;
    ahi[mt] = *(const f32x4*)(s0 + 4);
  }

  #pragma unroll
  for (int k = 0; k < NK; ++k) {
    bf16x8 wf[NTN];
    #pragma unroll
    for (int nt = 0; nt < NTN; ++nt) {
      const int wr = nt * 16 + lr;
      const int kg = (4 * k + quad) ^ (lr & 7);
      wf[nt] = *(const bf16x8*)(Wl + (size_t)wr * HDIM + kg * 8);
    }
    bf16x8 abf[NMT];
    #pragma unroll
    for (int mt = 0; mt < NMT; ++mt) abf[mt] = cvt8(alo[mt], ahi[mt]);
    if (k + 1 < NK) {
      #pragma unroll
      for (int mt = 0; mt < NMT; ++mt) {
        const float* s1 = Ab + (size_t)mt * 16 * HDIM + (k + 1) * BK;
        alo[mt] = *(const f32x4*)s1;
        ahi[mt] = *(const f32x4*)(s1 + 4);
      }
    }
    __builtin_amdgcn_s_setprio(1);
    #pragma unroll
    for (int mt = 0; mt < NMT; ++mt)
      #pragma unroll
      for (int nt = 0; nt < NTN; ++nt)
        acc[mt][nt] = __builtin_amdgcn_mfma_f32_16x16x32_bf16(
            abf[mt], wf[nt], acc[mt][nt], 0, 0, 0);
    __builtin_amdgcn_s_setprio(0);
  }

  // ---- Epilogue v2: atomic-free ----
  // Wait for ALL waves to finish reading Wl, then alias it as fp16 pooled.
  __syncthreads();
  __half* P = reinterpret_cast<__half*>(Wl);   // [BN][PSTR] col-major tile

  // Pass 1: tanh + pooled[:,0] + stage pooled into LDS.
  // C/D layout: col=lane&15, row=quad*4+reg (validated R3/R4).
  // Thread's 4 r-values are 4 consecutive rows at one col -> one ds_write_b64.
  #pragma unroll
  for (int nt = 0; nt < NTN; ++nt) {
    const int col = nt * 16 + lr;            // 0..95
    const float bv = bias_s[col];
    #pragma unroll
    for (int mt = 0; mt < NMT; ++mt) {
      const int rowbase = wave * 32 + mt * 16 + quad * 4;   // local row, %4==0
      float v0 = fast_tanh(acc[mt][nt][0] + bv);
      float v1 = fast_tanh(acc[mt][nt][1] + bv);
      float v2 = fast_tanh(acc[mt][nt][2] + bv);
      float v3 = fast_tanh(acc[mt][nt][3] + bv);
      if (rowbase == 0) out[(size_t)p * HDIM + tile_n + col] = v0; // pooled[:,0]
      union { __half2 h2[2]; uint2 u; } pk;
      pk.h2[0] = __floats2half2_rn(v0, v1);
      pk.h2[1] = __floats2half2_rn(v2, v3);
      *(uint2*)(P + (size_t)col * PSTR + rowbase) = pk.u;
    }
  }
  __syncthreads();

  // Pass 2: span-mean reduction. Thread owns (s,c) pairs; serial fp32 sum of
  // fp16 rows (consecutive addresses, no atomics, no RMW).
  for (int i = tid; i < NSPAN * BN; i += THREADS) {
    const int s = i / BN, c = i % BN;
    const int st = sp_st[s], en = sp_en[s];
    const __half* pc = P + (size_t)c * PSTR;
    float sum = 0.f;
    for (int r = st; r < en; ++r) sum += __half2float(pc[r]);
    out[OFF_SENT + ((size_t)p * NSPAN + s) * HDIM + tile_n + c] = sum * inv_s[s];
  }

  // sentence_mask zeros.
  if (ntb == 0 && tid < NSPAN) out[OFF_MASK + p * NSPAN + tid] = 0.f;
}

extern "C" void kernel_launch(void* const* d_in, const int* in_sizes, int n_in,
                              void* d_out, int out_size, void* d_ws, size_t ws_size,
                              hipStream_t stream) {
  const float* hs  = (const float*)d_in[0];  // (64,512,768) fp32
  const float* w   = (const float*)d_in[1];  // (768,768) fp32
  const float* bsc = (const float*)d_in[2];  // (768,) fp32
  // d_in[3] attention_mask unused
  const int* spans = (const int*)d_in[4];    // (64,16,2) int32

  fused_kernel<<<dim3(NBLK), dim3(THREADS), 0, stream>>>(
      hs, w, bsc, spans, (float*)d_out);
}